// Round 1
// baseline (700.353 us; speedup 1.0000x reference)
//
#include <hip/hip_runtime.h>

// ComplexMul2dParallel: out[b,o,m] = sum_i in[b,i,m] * w[i,o,m]  (complex)
// B=32, Ci=Co=128, modes=64*65=4160. fp32, stored as (..., 2) = (re, im).
//
// Block: 8 consecutive modes, full 32x128 (b,o) output -> every tensor read
// from HBM exactly once (818 MB total). 512 threads:
//   t = [worker s: 6b][mode lane ml: 3b]; worker -> 8b x 8o register tile.
// K staged in LDS chunks of KC=4 (A: 9 KB, W: 36 KB, +1 float2 row pad).

#define NB   32
#define CI   128
#define CO   128
#define MODES 4160
#define MPB  8
#define KC   4
#define SA   9   // A row stride in float2 (8 + 1 pad)
#define SW   9   // W row stride in float2

__global__ __launch_bounds__(512, 2)
void cmul2d_kernel(const float* __restrict__ I,
                   const float* __restrict__ Wg,
                   float* __restrict__ O) {
    __shared__ float2 Ain[KC * NB * SA];   // 4*32*9*8  = 9216 B
    __shared__ float2 Wt [KC * CO * SW];   // 4*128*9*8 = 36864 B

    const int t  = threadIdx.x;
    const int m0 = blockIdx.x * MPB;
    const int ml = t & 7;        // mode lane (fast -> coalesced epilogue)
    const int s  = t >> 3;       // worker 0..63
    const int so = s & 15;       // o-group 0..15 (low 3 bits vary in-wave)
    const int sb = s >> 4;       // b-group 0..3

    const float2* __restrict__ Ig = (const float2*)I;
    const float2* __restrict__ Wl = (const float2*)Wg;
    float2* __restrict__ Og = (float2*)O;

    float accr[8][8];
    float acci[8][8];
#pragma unroll
    for (int r = 0; r < 8; ++r)
#pragma unroll
        for (int q = 0; q < 8; ++q) { accr[r][q] = 0.f; acci[r][q] = 0.f; }

    for (int k0 = 0; k0 < CI; k0 += KC) {
        __syncthreads();   // previous chunk's compute done before overwrite
        // ---- stage A: KC*32*8 = 1024 float2 ----
#pragma unroll
        for (int j = t; j < KC * NB * MPB; j += 512) {
            const int ml_ = j & 7;
            const int bb  = (j >> 3) & (NB - 1);
            const int kk  = j >> 8;
            Ain[kk * (NB * SA) + bb * SA + ml_] =
                Ig[(bb * CI + k0 + kk) * MODES + m0 + ml_];
        }
        // ---- stage W: KC*128*8 = 4096 float2 ----
#pragma unroll
        for (int j = t; j < KC * CO * MPB; j += 512) {
            const int ml_ = j & 7;
            const int oo  = (j >> 3) & (CO - 1);
            const int kk  = j >> 10;
            Wt[kk * (CO * SW) + oo * SW + ml_] =
                Wl[((k0 + kk) * CO + oo) * MODES + m0 + ml_];
        }
        __syncthreads();

        // ---- compute: 4 k-steps, 8x8 outer product each ----
#pragma unroll
        for (int kk = 0; kk < KC; ++kk) {
            float2 a[8], w[8];
#pragma unroll
            for (int r = 0; r < 8; ++r)
                a[r] = Ain[kk * (NB * SA) + (sb * 8 + r) * SA + ml];
#pragma unroll
            for (int q = 0; q < 8; ++q)
                w[q] = Wt[kk * (CO * SW) + (so * 8 + q) * SW + ml];
#pragma unroll
            for (int r = 0; r < 8; ++r)
#pragma unroll
                for (int q = 0; q < 8; ++q) {
                    accr[r][q] = fmaf(a[r].x,  w[q].x, accr[r][q]);
                    accr[r][q] = fmaf(-a[r].y, w[q].y, accr[r][q]);
                    acci[r][q] = fmaf(a[r].x,  w[q].y, acci[r][q]);
                    acci[r][q] = fmaf(a[r].y,  w[q].x, acci[r][q]);
                }
        }
    }

    // ---- epilogue: coalesced float2 stores (64B per mode-octet) ----
#pragma unroll
    for (int r = 0; r < 8; ++r) {
        const int b = sb * 8 + r;
#pragma unroll
        for (int q = 0; q < 8; ++q) {
            const int o = so * 8 + q;
            Og[(b * CO + o) * MODES + m0 + ml] =
                make_float2(accr[r][q], acci[r][q]);
        }
    }
}

extern "C" void kernel_launch(void* const* d_in, const int* in_sizes, int n_in,
                              void* d_out, int out_size, void* d_ws, size_t ws_size,
                              hipStream_t stream) {
    const float* I  = (const float*)d_in[0];
    const float* Wg = (const float*)d_in[1];
    float* O = (float*)d_out;
    dim3 grid(MODES / MPB);   // 520 blocks
    dim3 block(512);
    cmul2d_kernel<<<grid, block, 0, stream>>>(I, Wg, O);
}

// Round 2
// 341.500 us; speedup vs baseline: 2.0508x; 2.0508x over previous
//
#include <hip/hip_runtime.h>

// out[b,o,m] = sum_i in[b,i,m] * w[i,o,m]  (complex, fp32)
// B=32, Ci=Co=128, M=64*65=4160. Stored (..., 2) = (re, im) -> one float2/elem.
//
// Block: MPB=4 modes, full 32b x 128o output. 512 thr: t=[worker:7][ml:2].
// Worker: 8b x 4o register tile (64 f2 acc). K in LDS chunks of KC=4,
// register-prefetch pipeline (issue chunk c+1 loads before computing c).
// Complex MAC = 2x v_pk_fma_f32 (packed fp32 = the 157 TF path).
// Pair-preserving XCD swizzle keeps mode-quad pairs (one 64B line) on one L2.

typedef float f2 __attribute__((ext_vector_type(2)));

#define NB 32
#define CI 128
#define CO 128
#define MODES 4160
#define MPB 4
#define KC 4
#define SA 5            // A row stride in f2 (4 + 1 pad)
#define SW 5            // W row stride in f2
#define NCHUNK (CI / KC)

// acc.lo += a.lo*w.lo - a.hi*w.hi ; acc.hi += a.lo*w.hi + a.hi*w.lo
#define CFMA(acc, av, wv)                                                      \
  asm("v_pk_fma_f32 %0, %1, %2, %0 op_sel:[0,0,0] op_sel_hi:[0,1,1]"           \
      : "+v"(acc) : "v"(av), "v"(wv));                                         \
  asm("v_pk_fma_f32 %0, %1, %2, %0 op_sel:[1,1,0] op_sel_hi:[1,0,1] "          \
      "neg_lo:[1,0,0]"                                                         \
      : "+v"(acc) : "v"(av), "v"(wv));

__global__ __launch_bounds__(512, 4)
void cmul2d_kernel(const f2* __restrict__ Ig,
                   const f2* __restrict__ Wl,
                   f2* __restrict__ Og) {
    __shared__ f2 Ain[KC * NB * SA];   //  5.1 KB
    __shared__ f2 Wt [KC * CO * SW];   // 20.5 KB

    const int t = threadIdx.x;

    // pair-preserving XCD swizzle: blocks k*16+x and k*16+8+x (same x mod 8,
    // hence same XCD) cover the two adjacent mode-quads of one 64B line.
    const int bid  = blockIdx.x;
    const int x    = bid & 7;
    const int half = (bid >> 3) & 1;
    const int kq   = bid >> 4;                       // 0..64
    const int m0   = (((kq << 3) + x) * 2 + half) * MPB;

    const int ml = t & 3;          // mode lane
    const int s  = t >> 2;         // worker 0..127
    const int so = s & 31;         // o-group (4 cols each)
    const int sb = s >> 5;         // b-group (8 rows each)

    // staging ownership: A -> (kkA, bbA, ml), W -> (kk=i, oo=s, ml), i=0..3
    const int bbA = s & 31;
    const int kkA = t >> 7;

    const f2* Ia = Ig + (size_t)(bbA * CI + kkA) * MODES + m0 + ml;
    const f2* Wa = Wl + (size_t)s * MODES + m0 + ml;

    f2 acc[8][4];
#pragma unroll
    for (int r = 0; r < 8; ++r)
#pragma unroll
        for (int q = 0; q < 4; ++q) acc[r][q] = (f2)(0.0f);

    // prologue: prefetch chunk 0
    f2 pa = Ia[0];
    f2 pw[4];
#pragma unroll
    for (int i = 0; i < 4; ++i)
        pw[i] = Wa[(size_t)i * CO * MODES];

    for (int c = 0; c < NCHUNK; ++c) {
        __syncthreads();                       // chunk c-1 consumers done
        Ain[kkA * (NB * SA) + bbA * SA + ml] = pa;
#pragma unroll
        for (int i = 0; i < 4; ++i)
            Wt[i * (CO * SW) + s * SW + ml] = pw[i];
        __syncthreads();

        if (c + 1 < NCHUNK) {                  // issue chunk c+1, no wait:
            pa = Ia[(size_t)(c + 1) * KC * MODES];           // hides under
#pragma unroll
            for (int i = 0; i < 4; ++i)                       // the compute
                pw[i] = Wa[(size_t)((c + 1) * KC + i) * CO * MODES];
        }

#pragma unroll
        for (int kk = 0; kk < KC; ++kk) {
            f2 a[8], w[4];
#pragma unroll
            for (int r = 0; r < 8; ++r)
                a[r] = Ain[kk * (NB * SA) + (sb * 8 + r) * SA + ml];
#pragma unroll
            for (int q = 0; q < 4; ++q)
                w[q] = Wt[kk * (CO * SW) + (so * 4 + q) * SW + ml];
#pragma unroll
            for (int r = 0; r < 8; ++r)
#pragma unroll
                for (int q = 0; q < 4; ++q) {
                    CFMA(acc[r][q], a[r], w[q]);
                }
        }
    }

    // epilogue: one f2 store per output element (32B runs, pair-merged in L2)
#pragma unroll
    for (int r = 0; r < 8; ++r) {
        const int b = sb * 8 + r;
#pragma unroll
        for (int q = 0; q < 4; ++q) {
            const int o = so * 4 + q;
            Og[(size_t)(b * CO + o) * MODES + m0 + ml] = acc[r][q];
        }
    }
}

extern "C" void kernel_launch(void* const* d_in, const int* in_sizes, int n_in,
                              void* d_out, int out_size, void* d_ws, size_t ws_size,
                              hipStream_t stream) {
    const f2* I = (const f2*)d_in[0];
    const f2* W = (const f2*)d_in[1];
    f2* O = (f2*)d_out;
    dim3 grid(MODES / MPB);   // 1040
    dim3 block(512);
    cmul2d_kernel<<<grid, block, 0, stream>>>(I, W, O);
}